// Round 1
// baseline (722.221 us; speedup 1.0000x reference)
//
#include <hip/hip_runtime.h>
#include <cstdint>

// IFS fractal step (all float32):
//   tp = selu(points @ M[choice] + b[choice])         -> out[0 .. N*3)
//   new_colors = (prev_colors + colors[choice]) * 0.5 -> out[N*3 .. 2*N*3)
// Memory-bound: 872 MB total traffic, floor ~140 us @ 6.3 TB/s.
// All five streams are touch-once (>> LLC): use non-temporal (evict-first)
// loads AND stores so output allocation doesn't thrash the read streams.

typedef float v4f __attribute__((ext_vector_type(4)));
typedef int   v4i __attribute__((ext_vector_type(4)));

__device__ __forceinline__ float selu_f(float x) {
    const float alpha = 1.6732632423543772f;
    const float scale = 1.0507009873554805f;
    float neg = alpha * (__expf(x) - 1.0f);   // only used for x <= 0
    return scale * (x > 0.0f ? x : neg);
}

__global__ __launch_bounds__(256) void ifs_kernel(
    const float* __restrict__ points,       // [N,3]
    const float* __restrict__ prev_colors,  // [N,3]
    const int*   __restrict__ choices,      // [N]
    const float* __restrict__ matrices,     // [K,3,3] k*9 + d*3 + e
    const float* __restrict__ biases,       // [K,3]
    const float* __restrict__ colors,       // [K,3]
    float* __restrict__ out_tp,             // [N,3]
    float* __restrict__ out_col,            // [N,3]
    long long n_points)
{
    // LDS transform table, stride 17 floats: (17k + j) % 32 distinct for all k in [0,8)
    __shared__ float T[8][17];
    int tid = threadIdx.x;
    if (tid < 8 * 16) {
        int k = tid >> 4, j = tid & 15;
        float v = 0.0f;
        if (j < 9)       v = matrices[k * 9 + j];
        else if (j < 12) v = biases[k * 3 + (j - 9)];
        else if (j < 15) v = colors[k * 3 + (j - 12)];
        T[k][j] = v;
    }
    __syncthreads();

    long long g = (long long)blockIdx.x * blockDim.x + tid;
    long long base = g * 4;  // 4 points per thread
    if (base >= n_points) return;

    if (base + 4 <= n_points) {
        // points/prev_colors: 12 floats = 3x v4f; choices: 1x v4i — all non-temporal
        const v4f* pp = reinterpret_cast<const v4f*>(points + base * 3);
        const v4f* pc = reinterpret_cast<const v4f*>(prev_colors + base * 3);
        const v4i* cc = reinterpret_cast<const v4i*>(choices + base);

        v4f pv[3], cv[3];
        pv[0] = __builtin_nontemporal_load(pp + 0);
        pv[1] = __builtin_nontemporal_load(pp + 1);
        pv[2] = __builtin_nontemporal_load(pp + 2);
        cv[0] = __builtin_nontemporal_load(pc + 0);
        cv[1] = __builtin_nontemporal_load(pc + 1);
        cv[2] = __builtin_nontemporal_load(pc + 2);
        v4i ch = __builtin_nontemporal_load(cc);

        const float* pb = reinterpret_cast<const float*>(pv);
        const float* cb = reinterpret_cast<const float*>(cv);

        v4f ov[3], oc[3];
        float* ob  = reinterpret_cast<float*>(ov);
        float* ocb = reinterpret_cast<float*>(oc);

        #pragma unroll
        for (int j = 0; j < 4; ++j) {
            int k = ch[j] & 7;
            const float* t = T[k];
            float x = pb[3 * j + 0];
            float y = pb[3 * j + 1];
            float z = pb[3 * j + 2];
            // tp[e] = sum_d p[d] * M[d*3+e] + b[e]   (contract over FIRST axis of M)
            float e0 = fmaf(x, t[0], fmaf(y, t[3], fmaf(z, t[6], t[9])));
            float e1 = fmaf(x, t[1], fmaf(y, t[4], fmaf(z, t[7], t[10])));
            float e2 = fmaf(x, t[2], fmaf(y, t[5], fmaf(z, t[8], t[11])));
            ob[3 * j + 0] = selu_f(e0);
            ob[3 * j + 1] = selu_f(e1);
            ob[3 * j + 2] = selu_f(e2);
            ocb[3 * j + 0] = (cb[3 * j + 0] + t[12]) * 0.5f;
            ocb[3 * j + 1] = (cb[3 * j + 1] + t[13]) * 0.5f;
            ocb[3 * j + 2] = (cb[3 * j + 2] + t[14]) * 0.5f;
        }

        v4f* ot = reinterpret_cast<v4f*>(out_tp + base * 3);
        v4f* oo = reinterpret_cast<v4f*>(out_col + base * 3);
        __builtin_nontemporal_store(ov[0], ot + 0);
        __builtin_nontemporal_store(ov[1], ot + 1);
        __builtin_nontemporal_store(ov[2], ot + 2);
        __builtin_nontemporal_store(oc[0], oo + 0);
        __builtin_nontemporal_store(oc[1], oo + 1);
        __builtin_nontemporal_store(oc[2], oo + 2);
    } else {
        // scalar tail
        for (long long p = base; p < n_points; ++p) {
            int k = choices[p] & 7;
            const float* t = T[k];
            float x = points[p * 3 + 0];
            float y = points[p * 3 + 1];
            float z = points[p * 3 + 2];
            float e0 = fmaf(x, t[0], fmaf(y, t[3], fmaf(z, t[6], t[9])));
            float e1 = fmaf(x, t[1], fmaf(y, t[4], fmaf(z, t[7], t[10])));
            float e2 = fmaf(x, t[2], fmaf(y, t[5], fmaf(z, t[8], t[11])));
            out_tp[p * 3 + 0] = selu_f(e0);
            out_tp[p * 3 + 1] = selu_f(e1);
            out_tp[p * 3 + 2] = selu_f(e2);
            out_col[p * 3 + 0] = (prev_colors[p * 3 + 0] + t[12]) * 0.5f;
            out_col[p * 3 + 1] = (prev_colors[p * 3 + 1] + t[13]) * 0.5f;
            out_col[p * 3 + 2] = (prev_colors[p * 3 + 2] + t[14]) * 0.5f;
        }
    }
}

extern "C" void kernel_launch(void* const* d_in, const int* in_sizes, int n_in,
                              void* d_out, int out_size, void* d_ws, size_t ws_size,
                              hipStream_t stream) {
    const float* points      = (const float*)d_in[0];
    const float* prev_colors = (const float*)d_in[1];
    const int*   choices     = (const int*)d_in[2];
    const float* matrices    = (const float*)d_in[3];
    const float* biases      = (const float*)d_in[4];
    const float* colors      = (const float*)d_in[5];

    long long n = in_sizes[2];  // choices: one per point
    float* out_tp  = (float*)d_out;
    float* out_col = out_tp + (size_t)n * 3;

    long long n_threads = (n + 3) / 4;
    int block = 256;
    long long grid = (n_threads + block - 1) / block;
    ifs_kernel<<<(dim3)(unsigned int)grid, block, 0, stream>>>(
        points, prev_colors, choices, matrices, biases, colors,
        out_tp, out_col, n);
}